// Round 17
// baseline (237.816 us; speedup 1.0000x reference)
//
#include <hip/hip_runtime.h>

#define NPTS 8192
#define DIM 64
#define EPSF 1e-7f
#define LN2F 0.69314718055994531f
#define NBLK 1056      // sum_{by=0}^{31} (64 - 2*by)

typedef unsigned short u16;
typedef __attribute__((ext_vector_type(8))) short bf16x8;   // 8 bf16 (4 VGPRs)
typedef __attribute__((ext_vector_type(8))) unsigned short u16x8;
typedef __attribute__((ext_vector_type(4))) float f32x4;
typedef __attribute__((ext_vector_type(2))) float f32x2;

// ---- kernel 1: x -> bf16 (round-to-nearest); meta = {-sq/2, 1/(1-sq), -4/(1-sq), label}
// Also zeroes S, T, out.
__global__ void prep_kernel(const float* __restrict__ x, const int* __restrict__ labels,
                            u16* __restrict__ hi,
                            float4* __restrict__ meta,
                            float* __restrict__ S, float* __restrict__ T,
                            float* __restrict__ out) {
    int g = blockIdx.x * blockDim.x + threadIdx.x;   // 0 .. NPTS*8-1
    int row = g >> 3, sub = g & 7;
    const float* xp = x + row * DIM + sub * 8;
    float v[8];
    float s = 0.f;
#pragma unroll
    for (int k = 0; k < 8; k++) { v[k] = xp[k]; s = fmaf(v[k], v[k], s); }
    s += __shfl_xor(s, 1);
    s += __shfl_xor(s, 2);
    s += __shfl_xor(s, 4);
    u16x8 h;
#pragma unroll
    for (int k = 0; k < 8; k++) {
        unsigned int bits = __float_as_uint(v[k]);
        unsigned int r = bits + 0x7FFFu + ((bits >> 16) & 1u);   // RTN-even bf16
        h[k] = (u16)(r >> 16);
    }
    *(u16x8*)(hi + row * DIM + sub * 8) = h;
    if (sub == 0) {
        float r = 1.0f / (1.0f - s);
        meta[row] = make_float4(-0.5f * s, r, -4.0f * r, (float)labels[row]);
    } else if (sub == 1) {
        S[row] = 0.f;
    } else if (sub == 2) {
        T[row] = 0.f;
    }
    if (g == 3) out[0] = 0.f;
}

// C(b) = number of active tiles with by < b
__device__ __forceinline__ int cumtiles(int b) { return 65 * b - b * b; }

// ---- kernel 2: triangular fused MFMA Gram + hyperbolic epilogue -------------
// Static grid of all 1056 active tiles; 128(i) x 256(j), active iff bx>=2*by.
// Single bf16 product (R14 error budget). R17 body cuts: packed f32x2
// epilogue (v_pk_*), MFMA C-chaining (init carries the norms), j-side per-t
// partials in registers (t-loop fully unrolled) with the quad shuffles +
// atomics at the tile tail — zero LDS, zero in-loop DS ops, no syncthreads.
__global__ void __launch_bounds__(256, 3) pair_mfma(
        const u16* __restrict__ hi,
        const float4* __restrict__ meta,
        float* __restrict__ Sarr, float* __restrict__ Tarr) {
    int tid = threadIdx.x;
    int wave = tid >> 6, lane = tid & 63;
    int quad = lane >> 4, l15 = lane & 15;

    // invert linear tile id -> (by, bx) in the triangular tile set
    int bid = blockIdx.x;
    int by = (int)((65.0f - __builtin_amdgcn_sqrtf(4225.0f - 4.0f * (float)bid)) * 0.5f);
    while (cumtiles(by + 1) <= bid) by++;
    while (cumtiles(by) > bid) by--;
    int off = bid - cumtiles(by);
    int bx = 2 * by + off;
    bool full = (off >= 2);

    int i0 = bx * 128 + wave * 32;
    int j0 = by * 256;

    bf16x8 a_hi[2][2];
#pragma unroll
    for (int it = 0; it < 2; it++)
#pragma unroll
        for (int ks = 0; ks < 2; ks++) {
            int aoff = (i0 + it * 16 + l15) * DIM + ks * 32 + quad * 8;
            a_hi[it][ks] = *(const bf16x8*)(hi + aoff);
        }

    f32x4 hsqi4[2];          // -sq_i/2 for this lane's 8 rows
    f32x2 rcp2[4];           // 1/(1-sq_i) as packed pairs
    float labi[8];
#pragma unroll
    for (int it = 0; it < 2; it++)
#pragma unroll
        for (int r = 0; r < 4; r++) {
            float4 m = meta[i0 + it * 16 + quad * 4 + r];
            hsqi4[it][r] = m.x;
            rcp2[it * 2 + (r >> 1)][r & 1] = m.y;
            labi[it * 4 + r] = m.w;
        }

    f32x2 Sx2[4], Tx2[4];
#pragma unroll
    for (int k = 0; k < 4; k++) { Sx2[k] = (f32x2){0.f, 0.f}; Tx2[k] = (f32x2){0.f, 0.f}; }

    float psS[16], psT[16];  // per-t j-side partials (this lane's 8 rows)

#pragma unroll
    for (int t = 0; t < 16; t++) {
        int jg = j0 + t * 16 + l15;
        int boff = jg * DIM + quad * 8;
        bf16x8 b0 = *(const bf16x8*)(hi + boff);
        bf16x8 b1 = *(const bf16x8*)(hi + boff + 32);
        float4 mj = meta[jg];    // {hsqj, rcpomj, m4rj, labj}

        f32x2 sSum = (f32x2){0.f, 0.f}, tSum = (f32x2){0.f, 0.f};
#pragma unroll
        for (int it = 0; it < 2; it++) {
            f32x4 acc = hsqi4[it] + mj.x;          // norms folded via C operand
            acc = __builtin_amdgcn_mfma_f32_16x16x32_bf16(a_hi[it][0], b0, acc, 0, 0, 0);
            acc = __builtin_amdgcn_mfma_f32_16x16x32_bf16(a_hi[it][1], b1, acc, 0, 0, 0);

#pragma unroll
            for (int g = 0; g < 2; g++) {          // packed pairs (rows 2g, 2g+1)
                f32x2 D = (f32x2){acc[2 * g], acc[2 * g + 1]};
                f32x2 u = (D * rcp2[it * 2 + g]) * mj.z;
                u = __builtin_elementwise_max(u, (f32x2){EPSF, EPSF});
                f32x2 arg = u * u + (u + u);
                f32x2 srt = (f32x2){__builtin_amdgcn_sqrtf(arg.x), __builtin_amdgcn_sqrtf(arg.y)};
                f32x2 opu = u + 1.0f;
                f32x2 st = opu - srt;              // exp(-d)
                f32x2 w1 = opu + srt;              // exp(+d)
                f32x2 l2 = (f32x2){__builtin_amdgcn_logf(w1.x), __builtin_amdgcn_logf(w1.y)};
                f32x2 tv;
                tv.x = (mj.w == labi[it * 4 + 2 * g]) ? l2.x : 0.0f;
                tv.y = (mj.w == labi[it * 4 + 2 * g + 1]) ? l2.y : 0.0f;
                Sx2[it * 2 + g] += st;
                Tx2[it * 2 + g] += tv;
                sSum += st;
                tSum += tv;
            }
        }
        psS[t] = sSum.x + sSum.y;
        psT[t] = tSum.x + tSum.y;
    }

    // i-side: unpack and reduce across the 16 j-columns
    float Sx[8], Tx[8];
#pragma unroll
    for (int k = 0; k < 4; k++) {
        Sx[2 * k] = Sx2[k].x; Sx[2 * k + 1] = Sx2[k].y;
        Tx[2 * k] = Tx2[k].x; Tx[2 * k + 1] = Tx2[k].y;
    }
#pragma unroll
    for (int r = 0; r < 8; r++) {
#pragma unroll
        for (int m = 1; m < 16; m <<= 1) {
            Sx[r] += __shfl_xor(Sx[r], m);
            Tx[r] += __shfl_xor(Tx[r], m);
        }
    }
    if (l15 == 0) {
#pragma unroll
        for (int it = 0; it < 2; it++)
#pragma unroll
            for (int r = 0; r < 4; r++) {
                int row = i0 + it * 16 + quad * 4 + r;
                atomicAdd(&Sarr[row], Sx[it * 4 + r]);
                atomicAdd(&Tarr[row], Tx[it * 4 + r]);
            }
    }

    // j-side: quad-reduce the per-t partials, then direct atomics (full only)
    if (full) {
#pragma unroll
        for (int t = 0; t < 16; t++) {
            float s = psS[t], tt = psT[t];
            s += __shfl_xor(s, 16); s += __shfl_xor(s, 32);
            tt += __shfl_xor(tt, 16); tt += __shfl_xor(tt, 32);
            if (quad == 0) {
                int col = j0 + t * 16 + l15;
                atomicAdd(&Sarr[col], s);
                atomicAdd(&Tarr[col], tt);
            }
        }
    }
}

// ---- kernel 3: finalize, 32 parallel blocks ---------------------------------
__global__ void __launch_bounds__(256) finalize_kernel(
        const float* __restrict__ S, const float* __restrict__ T,
        const int* __restrict__ labels, float* __restrict__ out) {
    __shared__ int hist[16][16];
    __shared__ float cntf[16];
    __shared__ float red[256];
    int tid = threadIdx.x;
    hist[tid >> 4][tid & 15] = 0;
    __syncthreads();
    int rep = tid & 15;
    for (int i = tid; i < NPTS; i += 256)
        atomicAdd(&hist[rep][labels[i]], 1);
    __syncthreads();
    if (tid < 16) {
        int s = 0;
#pragma unroll
        for (int k = 0; k < 16; k++) s += hist[k][tid];
        cntf[tid] = (float)(s - 1);
    }
    __syncthreads();

    float s0 = __builtin_amdgcn_sqrtf(EPSF * (2.0f + EPSF));
    float st0 = 1.0f + EPSF - s0;                         // self exp(-d) term
    float l20 = __builtin_amdgcn_logf(1.0f + EPSF + s0);  // self log2 term
    int i = blockIdx.x * 256 + tid;
    float loss = __logf(S[i] - st0) + (T[i] - l20) * LN2F / cntf[labels[i]];
    red[tid] = loss;
    __syncthreads();
    for (int s = 128; s > 0; s >>= 1) {
        if (tid < s) red[tid] += red[tid + s];
        __syncthreads();
    }
    if (tid == 0) atomicAdd(out, red[0]);
}

extern "C" void kernel_launch(void* const* d_in, const int* in_sizes, int n_in,
                              void* d_out, int out_size, void* d_ws, size_t ws_size,
                              hipStream_t stream) {
    const float* x = (const float*)d_in[0];
    const int* labels = (const int*)d_in[1];

    u16* hi = (u16*)d_ws;                 // NPTS*DIM u16
    float4* meta = (float4*)(hi + NPTS * DIM);
    float* S = (float*)(meta + NPTS);
    float* T = S + NPTS;

    prep_kernel<<<(NPTS * 8) / 256, 256, 0, stream>>>(x, labels, hi, meta, S, T, (float*)d_out);

    pair_mfma<<<NBLK, 256, 0, stream>>>(hi, meta, S, T);

    finalize_kernel<<<NPTS / 256, 256, 0, stream>>>(S, T, labels, (float*)d_out);
}

// Round 18
// 103.387 us; speedup vs baseline: 2.3002x; 2.3002x over previous
//
#include <hip/hip_runtime.h>

#define NPTS 8192
#define DIM 64
#define EPSF 1e-7f
#define LN2F 0.69314718055994531f
#define NBLK 1056      // sum_{by=0}^{31} (64 - 2*by)

typedef unsigned short u16;
typedef __attribute__((ext_vector_type(8))) short bf16x8;   // 8 bf16 (4 VGPRs)
typedef __attribute__((ext_vector_type(8))) unsigned short u16x8;
typedef __attribute__((ext_vector_type(4))) float f32x4;
typedef __attribute__((ext_vector_type(2))) float f32x2;

// ---- kernel 1: x -> bf16 (round-to-nearest); meta = {-sq/2, 1/(1-sq), -4/(1-sq), label}
// Also zeroes S, T, out.
__global__ void prep_kernel(const float* __restrict__ x, const int* __restrict__ labels,
                            u16* __restrict__ hi,
                            float4* __restrict__ meta,
                            float* __restrict__ S, float* __restrict__ T,
                            float* __restrict__ out) {
    int g = blockIdx.x * blockDim.x + threadIdx.x;   // 0 .. NPTS*8-1
    int row = g >> 3, sub = g & 7;
    const float* xp = x + row * DIM + sub * 8;
    float v[8];
    float s = 0.f;
#pragma unroll
    for (int k = 0; k < 8; k++) { v[k] = xp[k]; s = fmaf(v[k], v[k], s); }
    s += __shfl_xor(s, 1);
    s += __shfl_xor(s, 2);
    s += __shfl_xor(s, 4);
    u16x8 h;
#pragma unroll
    for (int k = 0; k < 8; k++) {
        unsigned int bits = __float_as_uint(v[k]);
        unsigned int r = bits + 0x7FFFu + ((bits >> 16) & 1u);   // RTN-even bf16
        h[k] = (u16)(r >> 16);
    }
    *(u16x8*)(hi + row * DIM + sub * 8) = h;
    if (sub == 0) {
        float r = 1.0f / (1.0f - s);
        meta[row] = make_float4(-0.5f * s, r, -4.0f * r, (float)labels[row]);
    } else if (sub == 1) {
        S[row] = 0.f;
    } else if (sub == 2) {
        T[row] = 0.f;
    }
    if (g == 3) out[0] = 0.f;
}

// C(b) = number of active tiles with by < b
__device__ __forceinline__ int cumtiles(int b) { return 65 * b - b * b; }

// ---- kernel 2: triangular fused MFMA Gram + hyperbolic epilogue -------------
// R16 champion structure (static 1056 tiles, LDS j-slab, reg dbuf, unroll 2)
// with ONLY the epilogue packed to f32x2 (v_pk_*). R17's psS[16] register
// arrays + full unroll spill-bombed (339MB scratch writes) — LDS slab stays.
__global__ void __launch_bounds__(256, 4) pair_mfma(
        const u16* __restrict__ hi,
        const float4* __restrict__ meta,
        float* __restrict__ Sarr, float* __restrict__ Tarr) {
    __shared__ float slabS[4][256], slabT[4][256];

    int tid = threadIdx.x;
    int wave = tid >> 6, lane = tid & 63;
    int quad = lane >> 4, l15 = lane & 15;

    // invert linear tile id -> (by, bx) in the triangular tile set
    int bid = blockIdx.x;
    int by = (int)((65.0f - __builtin_amdgcn_sqrtf(4225.0f - 4.0f * (float)bid)) * 0.5f);
    while (cumtiles(by + 1) <= bid) by++;
    while (cumtiles(by) > bid) by--;
    int off = bid - cumtiles(by);
    int bx = 2 * by + off;
    bool full = (off >= 2);

    int i0 = bx * 128 + wave * 32;
    int j0 = by * 256;

    bf16x8 a_hi[2][2];
#pragma unroll
    for (int it = 0; it < 2; it++)
#pragma unroll
        for (int ks = 0; ks < 2; ks++) {
            int aoff = (i0 + it * 16 + l15) * DIM + ks * 32 + quad * 8;
            a_hi[it][ks] = *(const bf16x8*)(hi + aoff);
        }

    f32x4 hsqi4[2];          // -sq_i/2 for this lane's 8 rows (C-init vector)
    f32x2 rcp2[4];           // 1/(1-sq_i) packed pairs
    float labi[8];
#pragma unroll
    for (int it = 0; it < 2; it++)
#pragma unroll
        for (int r = 0; r < 4; r++) {
            float4 m = meta[i0 + it * 16 + quad * 4 + r];
            hsqi4[it][r] = m.x;
            rcp2[it * 2 + (r >> 1)][r & 1] = m.y;
            labi[it * 4 + r] = m.w;
        }

    if (full) {
        slabS[wave][lane] = 0.f;       slabT[wave][lane] = 0.f;
        slabS[wave][lane + 64] = 0.f;  slabT[wave][lane + 64] = 0.f;
        slabS[wave][lane + 128] = 0.f; slabT[wave][lane + 128] = 0.f;
        slabS[wave][lane + 192] = 0.f; slabT[wave][lane + 192] = 0.f;
    }

    f32x2 Sx2[4], Tx2[4];
#pragma unroll
    for (int k = 0; k < 4; k++) { Sx2[k] = (f32x2){0.f, 0.f}; Tx2[k] = (f32x2){0.f, 0.f}; }

    // register double-buffer: B fragments + meta for the next t
    bf16x8 bh[2][2];
    float4 mjb[2];
    {
        int boff = (j0 + l15) * DIM + quad * 8;
        bh[0][0] = *(const bf16x8*)(hi + boff);
        bh[0][1] = *(const bf16x8*)(hi + boff + 32);
        mjb[0] = meta[j0 + l15];
    }

#pragma unroll 2
    for (int t = 0; t < 16; t++) {
        int cur = t & 1, nxt = cur ^ 1;
        if (t < 15) {
            int jgn = j0 + (t + 1) * 16 + l15;
            int boff = jgn * DIM + quad * 8;
            bh[nxt][0] = *(const bf16x8*)(hi + boff);
            bh[nxt][1] = *(const bf16x8*)(hi + boff + 32);
            mjb[nxt] = meta[jgn];
        }
        float4 mj = mjb[cur];    // {hsqj, rcpomj, m4rj, labj}

        f32x2 sSum = (f32x2){0.f, 0.f}, tSum = (f32x2){0.f, 0.f};
#pragma unroll
        for (int it = 0; it < 2; it++) {
            f32x4 acc = hsqi4[it] + mj.x;          // norms folded via C operand
            acc = __builtin_amdgcn_mfma_f32_16x16x32_bf16(a_hi[it][0], bh[cur][0], acc, 0, 0, 0);
            acc = __builtin_amdgcn_mfma_f32_16x16x32_bf16(a_hi[it][1], bh[cur][1], acc, 0, 0, 0);

#pragma unroll
            for (int g = 0; g < 2; g++) {          // packed pairs (rows 2g, 2g+1)
                f32x2 D = (f32x2){acc[2 * g], acc[2 * g + 1]};
                f32x2 u = (D * rcp2[it * 2 + g]) * mj.z;
                u = __builtin_elementwise_max(u, (f32x2){EPSF, EPSF});
                f32x2 arg = u * u + (u + u);
                f32x2 srt = (f32x2){__builtin_amdgcn_sqrtf(arg.x), __builtin_amdgcn_sqrtf(arg.y)};
                f32x2 opu = u + 1.0f;
                f32x2 st = opu - srt;              // exp(-d)
                f32x2 w1 = opu + srt;              // exp(+d)
                f32x2 l2;
                l2.x = __builtin_amdgcn_logf(w1.x);
                l2.y = __builtin_amdgcn_logf(w1.y);
                f32x2 tv;
                tv.x = (mj.w == labi[it * 4 + 2 * g]) ? l2.x : 0.0f;
                tv.y = (mj.w == labi[it * 4 + 2 * g + 1]) ? l2.y : 0.0f;
                Sx2[it * 2 + g] += st;
                Tx2[it * 2 + g] += tv;
                sSum += st;
                tSum += tv;
            }
        }

        if (full) {
            float pS = sSum.x + sSum.y, pT = tSum.x + tSum.y;
            pS += __shfl_xor(pS, 16); pS += __shfl_xor(pS, 32);
            pT += __shfl_xor(pT, 16); pT += __shfl_xor(pT, 32);
            if (quad == 0) {
                int c = t * 16 + l15;
                slabS[wave][c] += pS;
                slabT[wave][c] += pT;
            }
        }
    }

    // i-side: unpack and reduce across the 16 j-columns
    float Sx[8], Tx[8];
#pragma unroll
    for (int k = 0; k < 4; k++) {
        Sx[2 * k] = Sx2[k].x; Sx[2 * k + 1] = Sx2[k].y;
        Tx[2 * k] = Tx2[k].x; Tx[2 * k + 1] = Tx2[k].y;
    }
#pragma unroll
    for (int r = 0; r < 8; r++) {
#pragma unroll
        for (int m = 1; m < 16; m <<= 1) {
            Sx[r] += __shfl_xor(Sx[r], m);
            Tx[r] += __shfl_xor(Tx[r], m);
        }
    }
    if (l15 == 0) {
#pragma unroll
        for (int it = 0; it < 2; it++)
#pragma unroll
            for (int r = 0; r < 4; r++) {
                int row = i0 + it * 16 + quad * 4 + r;
                atomicAdd(&Sarr[row], Sx[it * 4 + r]);
                atomicAdd(&Tarr[row], Tx[it * 4 + r]);
            }
    }

    // j-side: flush per-wave slabs (full tiles only; block-uniform branch)
    if (full) {
        __syncthreads();
        float s = slabS[0][tid] + slabS[1][tid] + slabS[2][tid] + slabS[3][tid];
        float tt = slabT[0][tid] + slabT[1][tid] + slabT[2][tid] + slabT[3][tid];
        atomicAdd(&Sarr[j0 + tid], s);
        atomicAdd(&Tarr[j0 + tid], tt);
    }
}

// ---- kernel 3: finalize, 32 parallel blocks ---------------------------------
__global__ void __launch_bounds__(256) finalize_kernel(
        const float* __restrict__ S, const float* __restrict__ T,
        const int* __restrict__ labels, float* __restrict__ out) {
    __shared__ int hist[16][16];
    __shared__ float cntf[16];
    __shared__ float red[256];
    int tid = threadIdx.x;
    hist[tid >> 4][tid & 15] = 0;
    __syncthreads();
    int rep = tid & 15;
    for (int i = tid; i < NPTS; i += 256)
        atomicAdd(&hist[rep][labels[i]], 1);
    __syncthreads();
    if (tid < 16) {
        int s = 0;
#pragma unroll
        for (int k = 0; k < 16; k++) s += hist[k][tid];
        cntf[tid] = (float)(s - 1);
    }
    __syncthreads();

    float s0 = __builtin_amdgcn_sqrtf(EPSF * (2.0f + EPSF));
    float st0 = 1.0f + EPSF - s0;                         // self exp(-d) term
    float l20 = __builtin_amdgcn_logf(1.0f + EPSF + s0);  // self log2 term
    int i = blockIdx.x * 256 + tid;
    float loss = __logf(S[i] - st0) + (T[i] - l20) * LN2F / cntf[labels[i]];
    red[tid] = loss;
    __syncthreads();
    for (int s = 128; s > 0; s >>= 1) {
        if (tid < s) red[tid] += red[tid + s];
        __syncthreads();
    }
    if (tid == 0) atomicAdd(out, red[0]);
}

extern "C" void kernel_launch(void* const* d_in, const int* in_sizes, int n_in,
                              void* d_out, int out_size, void* d_ws, size_t ws_size,
                              hipStream_t stream) {
    const float* x = (const float*)d_in[0];
    const int* labels = (const int*)d_in[1];

    u16* hi = (u16*)d_ws;                 // NPTS*DIM u16
    float4* meta = (float4*)(hi + NPTS * DIM);
    float* S = (float*)(meta + NPTS);
    float* T = S + NPTS;

    prep_kernel<<<(NPTS * 8) / 256, 256, 0, stream>>>(x, labels, hi, meta, S, T, (float*)d_out);

    pair_mfma<<<NBLK, 256, 0, stream>>>(hi, meta, S, T);

    finalize_kernel<<<NPTS / 256, 256, 0, stream>>>(S, T, labels, (float*)d_out);
}